// Round 1
// baseline (2792.204 us; speedup 1.0000x reference)
//
#include <hip/hip_runtime.h>
#include <math.h>

#define BSZ 4
#define DD 48
#define SS (48*48*48)          // 110592 spatial per (b, channel)
#define NV (BSZ*SS)            // 442368 = total voxels per channel over batch
#define EPSBN 1e-5f

__device__ __forceinline__ float sigmoidf_(float x){ return 1.f/(1.f+expf(-x)); }

// ---------------- deformable conv stage ----------------
// x: (4,48,48,48) stage input.  y: (4,48,48,48) raw deform-conv output.
// p_out (if WRITE_P): (4,48,48,48,81) clipped sample positions.
template<bool WRITE_P>
__global__ __launch_bounds__(256) void deform_kernel(
    const float* __restrict__ x,
    const float* __restrict__ w_p, const float* __restrict__ b_p,
    const float* __restrict__ w_m, const float* __restrict__ b_m,
    const float* __restrict__ w_dc,
    float* __restrict__ y, float* __restrict__ p_out)
{
  __shared__ float s_wp[81*27];
  __shared__ float s_wm[27*27];
  __shared__ float s_bp[81];
  __shared__ float s_bm[27];
  __shared__ float s_wdc[27];
  for (int i=threadIdx.x;i<81*27;i+=blockDim.x) s_wp[i]=w_p[i];
  for (int i=threadIdx.x;i<27*27;i+=blockDim.x) s_wm[i]=w_m[i];
  for (int i=threadIdx.x;i<81;i+=blockDim.x)    s_bp[i]=b_p[i];
  for (int i=threadIdx.x;i<27;i+=blockDim.x)    s_bm[i]=b_m[i];
  for (int i=threadIdx.x;i<27;i+=blockDim.x)    s_wdc[i]=w_dc[i];
  __syncthreads();

  int idx = blockIdx.x*blockDim.x + threadIdx.x;
  if (idx >= NV) return;
  int b = idx / SS; int s = idx - b*SS;
  int d = s / (DD*DD); int r2 = s - d*DD*DD; int h = r2/DD; int w = r2 - h*DD;
  const float* xb = x + (size_t)b*SS;

  // 3x3x3 neighborhood of the stage input (zero-padded), used for both convs
  float nb[27];
  #pragma unroll
  for (int kd=0;kd<3;++kd)
  #pragma unroll
  for (int kh=0;kh<3;++kh)
  #pragma unroll
  for (int kw=0;kw<3;++kw){
    int zz=d+kd-1, yy=h+kh-1, xx=w+kw-1;
    bool ok = ((unsigned)zz<48u)&&((unsigned)yy<48u)&&((unsigned)xx<48u);
    nb[kd*9+kh*3+kw] = ok ? xb[(zz*48+yy)*48+xx] : 0.f;
  }

  float acc = 0.f;
  #pragma unroll 1
  for (int n=0;n<27;++n){
    float od=s_bp[n], oh=s_bp[27+n], ow=s_bp[54+n], mm=s_bm[n];
    #pragma unroll
    for (int t=0;t<27;++t){
      float v=nb[t];
      od = fmaf(s_wp[ n     *27+t], v, od);
      oh = fmaf(s_wp[(27+n)*27+t], v, oh);
      ow = fmaf(s_wp[(54+n)*27+t], v, ow);
      mm = fmaf(s_wm[ n     *27+t], v, mm);
    }
    mm = sigmoidf_(mm);
    int kd=n/9; int kh=(n-kd*9)/3; int kw=n-kd*9-kh*3;
    // padded coords: p0 (=d+1) + pn (=kd-1) + offset
    float pd=(float)(d+kd)+od, ph=(float)(h+kh)+oh, pw=(float)(w+kw)+ow;

    float d0=fminf(fmaxf(floorf(pd),0.f),49.f); float d1=fminf(d0+1.f,49.f);
    float pdc=fminf(fmaxf(pd,0.f),49.f);
    float wd0=1.f+d0-pdc, wd1=1.f-d1+pdc;
    float h0=fminf(fmaxf(floorf(ph),0.f),49.f); float h1v=fminf(h0+1.f,49.f);
    float phc=fminf(fmaxf(ph,0.f),49.f);
    float wh0=1.f+h0-phc, wh1=1.f-h1v+phc;
    float w0=fminf(fmaxf(floorf(pw),0.f),49.f); float w1v=fminf(w0+1.f,49.f);
    float pwc=fminf(fmaxf(pw,0.f),49.f);
    float ww0=1.f+w0-pwc, ww1=1.f-w1v+pwc;

    // convert padded integer coords -> unpadded input coords (pad ring = 0)
    int id0=(int)d0-1, id1=(int)d1-1;
    int ih0=(int)h0-1, ih1=(int)h1v-1;
    int iw0=(int)w0-1, iw1=(int)w1v-1;

    auto smp=[&](int z,int yy2,int xx2)->float{
      return (((unsigned)z<48u)&&((unsigned)yy2<48u)&&((unsigned)xx2<48u))
               ? xb[(z*48+yy2)*48+xx2] : 0.f;
    };
    float v000=smp(id0,ih0,iw0), v001=smp(id0,ih0,iw1);
    float v010=smp(id0,ih1,iw0), v011=smp(id0,ih1,iw1);
    float v100=smp(id1,ih0,iw0), v101=smp(id1,ih0,iw1);
    float v110=smp(id1,ih1,iw0), v111=smp(id1,ih1,iw1);
    float sv = wd0*(wh0*(ww0*v000+ww1*v001)+wh1*(ww0*v010+ww1*v011))
             + wd1*(wh0*(ww0*v100+ww1*v101)+wh1*(ww0*v110+ww1*v111));
    acc += sv*mm*s_wdc[n];

    if (WRITE_P){
      size_t base=(size_t)idx*81;
      p_out[base+n]     = pdc;
      p_out[base+27+n]  = phc;
      p_out[base+54+n]  = pwc;
    }
  }
  y[idx]=acc;
}

// ---------------- BN stats: sum & sumsq per channel ----------------
// x layout: (B, nch, SS). Per-channel element count is always B*SS = NV.
__global__ __launch_bounds__(256) void bn_stats_kernel(
    const float* __restrict__ x, int nch, float* __restrict__ sums)
{
  int c = blockIdx.y;
  float s1=0.f, s2=0.f;
  for (int i=blockIdx.x*blockDim.x+threadIdx.x; i<NV; i+=gridDim.x*blockDim.x){
    int b=i/SS; int s=i-b*SS;
    float v = x[((size_t)b*nch+c)*SS + s];
    s1+=v; s2+=v*v;
  }
  __shared__ float r1[256], r2[256];
  r1[threadIdx.x]=s1; r2[threadIdx.x]=s2; __syncthreads();
  for (int o=128;o>0;o>>=1){
    if (threadIdx.x<o){ r1[threadIdx.x]+=r1[threadIdx.x+o]; r2[threadIdx.x]+=r2[threadIdx.x+o]; }
    __syncthreads();
  }
  if (threadIdx.x==0){ atomicAdd(&sums[2*c],r1[0]); atomicAdd(&sums[2*c+1],r2[0]); }
}

// ---------------- BN normalize + relu ----------------
__global__ __launch_bounds__(256) void bn_relu_kernel(
    const float* __restrict__ x, float* __restrict__ out,
    const float* __restrict__ sums, const float* __restrict__ gamma,
    const float* __restrict__ beta, int nch)
{
  size_t idx = (size_t)blockIdx.x*blockDim.x + threadIdx.x;
  size_t total = (size_t)BSZ*nch*SS;
  if (idx>=total) return;
  int c = (int)((idx/SS)%nch);
  float mu  = sums[2*c]  *(1.f/(float)NV);
  float var = sums[2*c+1]*(1.f/(float)NV) - mu*mu;
  float v = (x[idx]-mu)*rsqrtf(var+EPSBN)*gamma[c]+beta[c];
  out[idx] = fmaxf(v,0.f);
}

// ---------------- conv1: 1 -> 32 channels, 3^3, pad 1 ----------------
__global__ __launch_bounds__(256) void conv1_kernel(
    const float* __restrict__ x, const float* __restrict__ wt, float* __restrict__ out)
{
  __shared__ float sw[32*27];
  for (int i=threadIdx.x;i<32*27;i+=blockDim.x) sw[i]=wt[i];
  __syncthreads();
  int idx = blockIdx.x*blockDim.x + threadIdx.x;
  if (idx >= NV) return;
  int b = idx / SS; int s = idx - b*SS;
  int d = s / (DD*DD); int r2 = s - d*DD*DD; int h = r2/DD; int w = r2 - h*DD;
  const float* xb = x + (size_t)b*SS;
  float nb[27];
  #pragma unroll
  for (int kd=0;kd<3;++kd)
  #pragma unroll
  for (int kh=0;kh<3;++kh)
  #pragma unroll
  for (int kw=0;kw<3;++kw){
    int zz=d+kd-1, yy=h+kh-1, xx=w+kw-1;
    bool ok = ((unsigned)zz<48u)&&((unsigned)yy<48u)&&((unsigned)xx<48u);
    nb[kd*9+kh*3+kw] = ok ? xb[(zz*48+yy)*48+xx] : 0.f;
  }
  #pragma unroll 1
  for (int c=0;c<32;++c){
    float a=0.f;
    #pragma unroll
    for (int t=0;t<27;++t) a = fmaf(sw[c*27+t], nb[t], a);
    out[((size_t)b*32+c)*SS + s] = a;
  }
}

// ---------------- conv2: 32 -> 16 channels of group g ----------------
__global__ __launch_bounds__(256) void conv2_kernel(
    const float* __restrict__ h1, const float* __restrict__ wt,
    float* __restrict__ out, int g)
{
  __shared__ float sw[16*32*27];   // 55.3 KB: this group's weight slice
  for (int i=threadIdx.x;i<16*32*27;i+=blockDim.x) sw[i]=wt[(size_t)g*16*32*27 + i];
  __syncthreads();
  int idx = blockIdx.x*blockDim.x + threadIdx.x;
  if (idx >= NV) return;
  int b = idx / SS; int s = idx - b*SS;
  int d = s / (DD*DD); int r2 = s - d*DD*DD; int h = r2/DD; int w = r2 - h*DD;

  float acc[16];
  #pragma unroll
  for (int i=0;i<16;++i) acc[i]=0.f;

  #pragma unroll 1
  for (int cin=0;cin<32;++cin){
    const float* xb = h1 + ((size_t)b*32+cin)*SS;
    float nb[27];
    #pragma unroll
    for (int kd=0;kd<3;++kd)
    #pragma unroll
    for (int kh=0;kh<3;++kh)
    #pragma unroll
    for (int kw=0;kw<3;++kw){
      int zz=d+kd-1, yy=h+kh-1, xx=w+kw-1;
      bool ok = ((unsigned)zz<48u)&&((unsigned)yy<48u)&&((unsigned)xx<48u);
      nb[kd*9+kh*3+kw] = ok ? xb[(zz*48+yy)*48+xx] : 0.f;
    }
    #pragma unroll 1
    for (int co=0;co<16;++co){
      const float* wp = &sw[(co*32+cin)*27];
      float a=acc[co];
      #pragma unroll
      for (int t=0;t<27;++t) a = fmaf(wp[t], nb[t], a);
      acc[co]=a;
    }
  }
  #pragma unroll
  for (int co=0;co<16;++co) out[((size_t)b*16+co)*SS + s] = acc[co];
}

// ---------------- BN + relu + 3^3/3 maxpool + spatial-sum ----------------
// t2: (4,16,48^3) group buffer. pooled: (4,64) accumulates sum of pooled maxima.
__global__ __launch_bounds__(256) void pool_kernel(
    const float* __restrict__ t2, const float* __restrict__ sums,
    const float* __restrict__ gamma, const float* __restrict__ beta,
    float* __restrict__ pooled, int g)
{
  int b = blockIdx.z, cl = blockIdx.y;
  int cell = blockIdx.x*blockDim.x + threadIdx.x;   // 0..4095 (16 blocks x 256)
  int pd = cell>>8; int rr = cell&255; int phh = rr>>4; int pww = rr&15;
  int cg = g*16 + cl;
  float mu  = sums[2*cl]  *(1.f/(float)NV);
  float var = sums[2*cl+1]*(1.f/(float)NV) - mu*mu;
  float sc  = rsqrtf(var+EPSBN)*gamma[cg];
  float sh  = beta[cg] - mu*sc;
  const float* base = t2 + ((size_t)b*16+cl)*SS;
  float mx = -1e30f;
  #pragma unroll
  for (int kd=0;kd<3;++kd)
  #pragma unroll
  for (int kh=0;kh<3;++kh)
  #pragma unroll
  for (int kw=0;kw<3;++kw){
    float v = base[((pd*3+kd)*48 + (phh*3+kh))*48 + (pww*3+kw)];
    v = fmaxf(fmaf(v,sc,sh), 0.f);
    mx = fmaxf(mx, v);
  }
  __shared__ float r[256];
  r[threadIdx.x]=mx; __syncthreads();
  for (int o=128;o>0;o>>=1){
    if (threadIdx.x<o) r[threadIdx.x]+=r[threadIdx.x+o];
    __syncthreads();
  }
  if (threadIdx.x==0) atomicAdd(&pooled[b*64+cg], r[0]);
}

// ---------------- FC head ----------------
__global__ void fc_kernel(const float* __restrict__ pooled,
                          const float* __restrict__ w_fc, const float* __restrict__ b_fc,
                          float* __restrict__ logits)
{
  int t = threadIdx.x;
  if (t < 40){
    int b = t/10, k = t - 10*(t/10);
    float a = b_fc[k];
    #pragma unroll 1
    for (int c=0;c<64;++c) a = fmaf(pooled[b*64+c]*(1.f/4096.f), w_fc[k*64+c], a);
    logits[b*10+k] = a;
  }
}

extern "C" void kernel_launch(void* const* d_in, const int* in_sizes, int n_in,
                              void* d_out, int out_size, void* d_ws, size_t ws_size,
                              hipStream_t stream)
{
  const float* x    = (const float*)d_in[0];
  const float* w_p  = (const float*)d_in[1];
  const float* b_p  = (const float*)d_in[2];
  const float* w_m  = (const float*)d_in[3];
  const float* b_m  = (const float*)d_in[4];
  const float* w_dc = (const float*)d_in[5];
  const float* g_d  = (const float*)d_in[6];
  const float* be_d = (const float*)d_in[7];
  const float* w_c1 = (const float*)d_in[8];
  const float* g1   = (const float*)d_in[9];
  const float* be1  = (const float*)d_in[10];
  const float* w_c2 = (const float*)d_in[11];
  const float* g2   = (const float*)d_in[12];
  const float* be2  = (const float*)d_in[13];
  const float* w_fc = (const float*)d_in[14];
  const float* b_fc = (const float*)d_in[15];

  float* out    = (float*)d_out;
  float* logits = out;                 // 40
  float* xxx    = out + 40;            // NV  (stage-2 raw y)
  float* p_out  = out + 40 + NV;       // NV*81

  // workspace layout (floats): total ~22.1M floats = 88.5 MB
  float* ws     = (float*)d_ws;
  float* inp    = ws;                  // NV   (BN+relu output, stage input)
  float* y1     = inp + NV;            // NV   (stage-1 raw y)
  float* stats  = y1  + NV;            // 128  (sum/sumsq pairs)
  float* pooled = stats + 128;         // 256  ((4,64) pooled sums)
  float* h1b    = pooled + 256;        // 4*32*SS = 14155776
  float* t2     = h1b + (size_t)4*32*SS; // 4*16*SS = 7077888

  const int nblk = (NV + 255)/256;     // 1728

  // ---- deform stage 1 ----
  deform_kernel<false><<<nblk,256,0,stream>>>(x, w_p,b_p,w_m,b_m,w_dc, y1, nullptr);
  hipMemsetAsync(stats, 0, 2*sizeof(float), stream);
  bn_stats_kernel<<<dim3(64,1),256,0,stream>>>(y1, 1, stats);
  bn_relu_kernel<<<nblk,256,0,stream>>>(y1, inp, stats, g_d, be_d, 1);

  // ---- deform stage 2 (writes xxx and p) ----
  deform_kernel<true><<<nblk,256,0,stream>>>(inp, w_p,b_p,w_m,b_m,w_dc, xxx, p_out);
  hipMemsetAsync(stats, 0, 2*sizeof(float), stream);
  bn_stats_kernel<<<dim3(64,1),256,0,stream>>>(xxx, 1, stats);
  bn_relu_kernel<<<nblk,256,0,stream>>>(xxx, inp, stats, g_d, be_d, 1);

  // ---- conv1 + BN + relu (in place) ----
  conv1_kernel<<<nblk,256,0,stream>>>(inp, w_c1, h1b);
  hipMemsetAsync(stats, 0, 64*sizeof(float), stream);
  bn_stats_kernel<<<dim3(64,32),256,0,stream>>>(h1b, 32, stats);
  bn_relu_kernel<<<32*nblk,256,0,stream>>>(h1b, h1b, stats, g1, be1, 32);

  // ---- conv2 in 4 groups of 16 channels: conv -> stats -> BN+relu+maxpool+sum ----
  hipMemsetAsync(pooled, 0, 256*sizeof(float), stream);
  for (int g=0; g<4; ++g){
    conv2_kernel<<<nblk,256,0,stream>>>(h1b, w_c2, t2, g);
    hipMemsetAsync(stats, 0, 32*sizeof(float), stream);
    bn_stats_kernel<<<dim3(64,16),256,0,stream>>>(t2, 16, stats);
    pool_kernel<<<dim3(16,16,BSZ),256,0,stream>>>(t2, stats, g2, be2, pooled, g);
  }

  // ---- FC head ----
  fc_kernel<<<1,64,0,stream>>>(pooled, w_fc, b_fc, logits);
}

// Round 2
// 868.616 us; speedup vs baseline: 3.2145x; 3.2145x over previous
//
#include <hip/hip_runtime.h>
#include <math.h>

#define BSZ 4
#define DD 48
#define SS (48*48*48)          // 110592 spatial per (b, channel)
#define NV (BSZ*SS)            // 442368 voxels per channel over batch
#define EPSBN 1e-5f

typedef __attribute__((ext_vector_type(8))) short bf16x8;
typedef __attribute__((ext_vector_type(4))) float f32x4;

__device__ __forceinline__ float sigmoidf_(float x){ return 1.f/(1.f+expf(-x)); }
__device__ __forceinline__ short f2b(float f){           // fp32 -> bf16 bits (RNE)
  unsigned u = __float_as_uint(f);
  u = (u + 0x7FFFu + ((u>>16)&1u)) >> 16;
  return (short)u;
}
__device__ __forceinline__ float b2f(short s){
  return __uint_as_float(((unsigned)(unsigned short)s)<<16);
}

// ---------------- deformable conv stage (unchanged fp32) ----------------
template<bool WRITE_P>
__global__ __launch_bounds__(256) void deform_kernel(
    const float* __restrict__ x,
    const float* __restrict__ w_p, const float* __restrict__ b_p,
    const float* __restrict__ w_m, const float* __restrict__ b_m,
    const float* __restrict__ w_dc,
    float* __restrict__ y, float* __restrict__ p_out)
{
  __shared__ float s_wp[81*27];
  __shared__ float s_wm[27*27];
  __shared__ float s_bp[81];
  __shared__ float s_bm[27];
  __shared__ float s_wdc[27];
  for (int i=threadIdx.x;i<81*27;i+=blockDim.x) s_wp[i]=w_p[i];
  for (int i=threadIdx.x;i<27*27;i+=blockDim.x) s_wm[i]=w_m[i];
  for (int i=threadIdx.x;i<81;i+=blockDim.x)    s_bp[i]=b_p[i];
  for (int i=threadIdx.x;i<27;i+=blockDim.x)    s_bm[i]=b_m[i];
  for (int i=threadIdx.x;i<27;i+=blockDim.x)    s_wdc[i]=w_dc[i];
  __syncthreads();

  int idx = blockIdx.x*blockDim.x + threadIdx.x;
  if (idx >= NV) return;
  int b = idx / SS; int s = idx - b*SS;
  int d = s / (DD*DD); int r2 = s - d*DD*DD; int h = r2/DD; int w = r2 - h*DD;
  const float* xb = x + (size_t)b*SS;

  float nb[27];
  #pragma unroll
  for (int kd=0;kd<3;++kd)
  #pragma unroll
  for (int kh=0;kh<3;++kh)
  #pragma unroll
  for (int kw=0;kw<3;++kw){
    int zz=d+kd-1, yy=h+kh-1, xx=w+kw-1;
    bool ok = ((unsigned)zz<48u)&&((unsigned)yy<48u)&&((unsigned)xx<48u);
    nb[kd*9+kh*3+kw] = ok ? xb[(zz*48+yy)*48+xx] : 0.f;
  }

  float acc = 0.f;
  #pragma unroll 1
  for (int n=0;n<27;++n){
    float od=s_bp[n], oh=s_bp[27+n], ow=s_bp[54+n], mm=s_bm[n];
    #pragma unroll
    for (int t=0;t<27;++t){
      float v=nb[t];
      od = fmaf(s_wp[ n     *27+t], v, od);
      oh = fmaf(s_wp[(27+n)*27+t], v, oh);
      ow = fmaf(s_wp[(54+n)*27+t], v, ow);
      mm = fmaf(s_wm[ n     *27+t], v, mm);
    }
    mm = sigmoidf_(mm);
    int kd=n/9; int kh=(n-kd*9)/3; int kw=n-kd*9-kh*3;
    float pd=(float)(d+kd)+od, ph=(float)(h+kh)+oh, pw=(float)(w+kw)+ow;

    float d0=fminf(fmaxf(floorf(pd),0.f),49.f); float d1=fminf(d0+1.f,49.f);
    float pdc=fminf(fmaxf(pd,0.f),49.f);
    float wd0=1.f+d0-pdc, wd1=1.f-d1+pdc;
    float h0=fminf(fmaxf(floorf(ph),0.f),49.f); float h1v=fminf(h0+1.f,49.f);
    float phc=fminf(fmaxf(ph,0.f),49.f);
    float wh0=1.f+h0-phc, wh1=1.f-h1v+phc;
    float w0=fminf(fmaxf(floorf(pw),0.f),49.f); float w1v=fminf(w0+1.f,49.f);
    float pwc=fminf(fmaxf(pw,0.f),49.f);
    float ww0=1.f+w0-pwc, ww1=1.f-w1v+pwc;

    int id0=(int)d0-1, id1=(int)d1-1;
    int ih0=(int)h0-1, ih1=(int)h1v-1;
    int iw0=(int)w0-1, iw1=(int)w1v-1;

    auto smp=[&](int z,int yy2,int xx2)->float{
      return (((unsigned)z<48u)&&((unsigned)yy2<48u)&&((unsigned)xx2<48u))
               ? xb[(z*48+yy2)*48+xx2] : 0.f;
    };
    float v000=smp(id0,ih0,iw0), v001=smp(id0,ih0,iw1);
    float v010=smp(id0,ih1,iw0), v011=smp(id0,ih1,iw1);
    float v100=smp(id1,ih0,iw0), v101=smp(id1,ih0,iw1);
    float v110=smp(id1,ih1,iw0), v111=smp(id1,ih1,iw1);
    float sv = wd0*(wh0*(ww0*v000+ww1*v001)+wh1*(ww0*v010+ww1*v011))
             + wd1*(wh0*(ww0*v100+ww1*v101)+wh1*(ww0*v110+ww1*v111));
    acc += sv*mm*s_wdc[n];

    if (WRITE_P){
      size_t base=(size_t)idx*81;
      p_out[base+n]     = pdc;
      p_out[base+27+n]  = phc;
      p_out[base+54+n]  = pwc;
    }
  }
  y[idx]=acc;
}

// ---------------- BN stats fp32 (deform stages, nch=1) ----------------
__global__ __launch_bounds__(256) void bn_stats_kernel(
    const float* __restrict__ x, int nch, float* __restrict__ sums)
{
  int c = blockIdx.y;
  float s1=0.f, s2=0.f;
  for (int i=blockIdx.x*blockDim.x+threadIdx.x; i<NV; i+=gridDim.x*blockDim.x){
    int b=i/SS; int s=i-b*SS;
    float v = x[((size_t)b*nch+c)*SS + s];
    s1+=v; s2+=v*v;
  }
  __shared__ float r1[256], r2[256];
  r1[threadIdx.x]=s1; r2[threadIdx.x]=s2; __syncthreads();
  for (int o=128;o>0;o>>=1){
    if (threadIdx.x<o){ r1[threadIdx.x]+=r1[threadIdx.x+o]; r2[threadIdx.x]+=r2[threadIdx.x+o]; }
    __syncthreads();
  }
  if (threadIdx.x==0){ atomicAdd(&sums[2*c],r1[0]); atomicAdd(&sums[2*c+1],r2[0]); }
}

// ---------------- BN normalize + relu fp32 (deform stages) ----------------
__global__ __launch_bounds__(256) void bn_relu_kernel(
    const float* __restrict__ x, float* __restrict__ out,
    const float* __restrict__ sums, const float* __restrict__ gamma,
    const float* __restrict__ beta, int nch)
{
  size_t idx = (size_t)blockIdx.x*blockDim.x + threadIdx.x;
  size_t total = (size_t)BSZ*nch*SS;
  if (idx>=total) return;
  int c = (int)((idx/SS)%nch);
  float mu  = sums[2*c]  *(1.f/(float)NV);
  float var = sums[2*c+1]*(1.f/(float)NV) - mu*mu;
  float v = (x[idx]-mu)*rsqrtf(var+EPSBN)*gamma[c]+beta[c];
  out[idx] = fmaxf(v,0.f);
}

// ---------------- BN stats over bf16 tensor ----------------
__global__ __launch_bounds__(256) void bn_stats_bf16(
    const short* __restrict__ x, int nch, float* __restrict__ sums)
{
  int c = blockIdx.y;
  const int S8 = SS/8;
  float s1=0.f, s2=0.f;
  for (int i8=blockIdx.x*blockDim.x+threadIdx.x; i8<BSZ*S8; i8+=gridDim.x*blockDim.x){
    int b=i8/S8; int s8=i8-b*S8;
    const bf16x8 v8 = *(const bf16x8*)(x + ((size_t)b*nch+c)*SS + (size_t)s8*8);
    #pragma unroll
    for (int j=0;j<8;++j){ float v=b2f(v8[j]); s1+=v; s2+=v*v; }
  }
  __shared__ float r1[256], r2[256];
  r1[threadIdx.x]=s1; r2[threadIdx.x]=s2; __syncthreads();
  for (int o=128;o>0;o>>=1){
    if (threadIdx.x<o){ r1[threadIdx.x]+=r1[threadIdx.x+o]; r2[threadIdx.x]+=r2[threadIdx.x+o]; }
    __syncthreads();
  }
  if (threadIdx.x==0){ atomicAdd(&sums[2*c],r1[0]); atomicAdd(&sums[2*c+1],r2[0]); }
}

// ---------------- BN + relu in place over bf16 tensor ----------------
__global__ __launch_bounds__(256) void bn_relu_bf16(
    short* __restrict__ x, const float* __restrict__ sums,
    const float* __restrict__ gamma, const float* __restrict__ beta, int nch)
{
  const int S8 = SS/8;
  size_t i8 = (size_t)blockIdx.x*blockDim.x + threadIdx.x;
  size_t total8 = (size_t)BSZ*nch*S8;
  if (i8>=total8) return;
  int c = (int)((i8/S8)%nch);
  float mu  = sums[2*c]  *(1.f/(float)NV);
  float var = sums[2*c+1]*(1.f/(float)NV) - mu*mu;
  float sc = rsqrtf(var+EPSBN)*gamma[c];
  float sh = beta[c] - mu*sc;
  bf16x8 v8 = *(bf16x8*)(x + i8*8);
  #pragma unroll
  for (int j=0;j<8;++j){
    float v = fmaxf(fmaf(b2f(v8[j]),sc,sh),0.f);
    v8[j] = f2b(v);
  }
  *(bf16x8*)(x + i8*8) = v8;
}

// ---------------- conv1: 1 -> 32 channels, fp32 in, bf16 out ----------------
__global__ __launch_bounds__(256) void conv1_kernel(
    const float* __restrict__ x, const float* __restrict__ wt, short* __restrict__ out)
{
  __shared__ float sw[32*27];
  for (int i=threadIdx.x;i<32*27;i+=blockDim.x) sw[i]=wt[i];
  __syncthreads();
  int idx = blockIdx.x*blockDim.x + threadIdx.x;
  if (idx >= NV) return;
  int b = idx / SS; int s = idx - b*SS;
  int d = s / (DD*DD); int r2 = s - d*DD*DD; int h = r2/DD; int w = r2 - h*DD;
  const float* xb = x + (size_t)b*SS;
  float nb[27];
  #pragma unroll
  for (int kd=0;kd<3;++kd)
  #pragma unroll
  for (int kh=0;kh<3;++kh)
  #pragma unroll
  for (int kw=0;kw<3;++kw){
    int zz=d+kd-1, yy=h+kh-1, xx=w+kw-1;
    bool ok = ((unsigned)zz<48u)&&((unsigned)yy<48u)&&((unsigned)xx<48u);
    nb[kd*9+kh*3+kw] = ok ? xb[(zz*48+yy)*48+xx] : 0.f;
  }
  #pragma unroll 1
  for (int c=0;c<32;++c){
    float a=0.f;
    #pragma unroll
    for (int t=0;t<27;++t) a = fmaf(sw[c*27+t], nb[t], a);
    out[((size_t)b*32+c)*SS + s] = f2b(a);
  }
}

// ---------------- conv2 weight repack: (co,ci,tap) fp32 -> (tap,co,ci) bf16 ----
__global__ void wconv_kernel(const float* __restrict__ w, short* __restrict__ wbf)
{
  int o = blockIdx.x*blockDim.x + threadIdx.x;
  if (o >= 27*64*32) return;
  int ci = o & 31; int co = (o>>5) & 63; int tap = o >> 11;
  wbf[o] = f2b(w[(co*32+ci)*27 + tap]);
}

// ---------------- conv2 via MFMA: 32 -> 64 channels, bf16 ----------------
// tile: 4(d) x 4(h) x 16(w) voxels per block; slab 6x6x18x32 bf16 in LDS.
// wave wid owns dz=wid; computes all 64 couts for its 64 voxels.
__global__ __launch_bounds__(256) void conv2_mfma(
    const short* __restrict__ h1, const short* __restrict__ wbf,
    short* __restrict__ t2)
{
  __shared__ __align__(16) short slab[6*6*18*32];  // 41472 B
  int bid = blockIdx.x;
  int bw = bid % 3; int bh = (bid/3)%12; int bd = (bid/36)%12; int b = bid/432;
  int d0 = bd*4, h0 = bh*4, w0 = bw*16;
  int tid = threadIdx.x;
  const short* hb = h1 + (size_t)b*32*SS;

  for (int e = tid; e < 648; e += 256){
    int z = e/108; int rem = e - z*108; int y = rem/18; int x = rem - y*18;
    int gd = d0-1+z, gh = h0-1+y, gw = w0-1+x;
    bool ok = ((unsigned)gd<48u)&&((unsigned)gh<48u)&&((unsigned)gw<48u);
    int gbase = ok ? (gd*48+gh)*48+gw : 0;
    int swz = (x&3)<<3;
    int lbase = e*32;
    #pragma unroll
    for (int ci=0; ci<32; ci+=2){
      short v0 = ok ? hb[(size_t)ci*SS + gbase] : (short)0;
      short v1 = ok ? hb[(size_t)(ci+1)*SS + gbase] : (short)0;
      int p0 = ci ^ swz;                      // swz is mult of 8: ci,ci+1 stay adjacent
      slab[lbase + p0]     = v0;
      slab[lbase + p0 + 1] = v1;
    }
  }
  __syncthreads();

  int lane = tid & 63, wid = tid >> 6;
  int q = lane >> 4, n16 = lane & 15;
  f32x4 zero4 = {0.f,0.f,0.f,0.f};
  f32x4 acc[4][4];
  #pragma unroll
  for (int i=0;i<4;++i)
  #pragma unroll
  for (int j=0;j<4;++j) acc[i][j] = zero4;

  #pragma unroll 1
  for (int tap=0; tap<27; ++tap){
    int kd = tap/9; int kh = (tap/3)%3; int kw = tap%3;
    const short* wp = wbf + (size_t)tap*64*32 + n16*32 + q*8;
    bf16x8 aF[4];
    #pragma unroll
    for (int mb=0; mb<4; ++mb)
      aF[mb] = *(const bf16x8*)(wp + mb*16*32);

    int xx = n16 + kw;
    int cof = (q ^ (xx&3)) << 3;
    int zz = wid + kd;
    bf16x8 bF[4];
    #pragma unroll
    for (int dy=0; dy<4; ++dy){
      int yy = dy + kh;
      bF[dy] = *(const bf16x8*)&slab[ ((zz*6 + yy)*18 + xx)*32 + cof ];
    }
    #pragma unroll
    for (int mb=0; mb<4; ++mb)
      #pragma unroll
      for (int dy=0; dy<4; ++dy)
        acc[mb][dy] = __builtin_amdgcn_mfma_f32_16x16x32_bf16(aF[mb], bF[dy], acc[mb][dy], 0,0,0);
  }

  int d = d0 + wid;
  #pragma unroll
  for (int mb=0; mb<4; ++mb)
  #pragma unroll
  for (int dy=0; dy<4; ++dy){
    int h = h0 + dy, w = w0 + n16;
    #pragma unroll
    for (int r=0; r<4; ++r){
      int c = mb*16 + q*4 + r;
      t2[ (size_t)(b*64+c)*SS + (d*48+h)*48 + w ] = f2b(acc[mb][dy][r]);
    }
  }
}

// ---------------- BN + relu + 3^3/3 maxpool + spatial-sum (bf16 in) ----------
__global__ __launch_bounds__(256) void pool64_kernel(
    const short* __restrict__ t2, const float* __restrict__ sums,
    const float* __restrict__ gamma, const float* __restrict__ beta,
    float* __restrict__ pooled)
{
  int b = blockIdx.z, c = blockIdx.y;
  int cell = blockIdx.x*blockDim.x + threadIdx.x;   // 0..4095
  int pd = cell>>8; int rr = cell&255; int phh = rr>>4; int pww = rr&15;
  float mu  = sums[2*c]  *(1.f/(float)NV);
  float var = sums[2*c+1]*(1.f/(float)NV) - mu*mu;
  float sc  = rsqrtf(var+EPSBN)*gamma[c];
  float sh  = beta[c] - mu*sc;
  const short* base = t2 + ((size_t)b*64+c)*SS;
  float mx = -1e30f;
  #pragma unroll
  for (int kd=0;kd<3;++kd)
  #pragma unroll
  for (int kh=0;kh<3;++kh)
  #pragma unroll
  for (int kw=0;kw<3;++kw){
    float v = b2f(base[((pd*3+kd)*48 + (phh*3+kh))*48 + (pww*3+kw)]);
    v = fmaxf(fmaf(v,sc,sh), 0.f);
    mx = fmaxf(mx, v);
  }
  __shared__ float r[256];
  r[threadIdx.x]=mx; __syncthreads();
  for (int o=128;o>0;o>>=1){
    if (threadIdx.x<o) r[threadIdx.x]+=r[threadIdx.x+o];
    __syncthreads();
  }
  if (threadIdx.x==0) atomicAdd(&pooled[b*64+c], r[0]);
}

// ---------------- FC head ----------------
__global__ void fc_kernel(const float* __restrict__ pooled,
                          const float* __restrict__ w_fc, const float* __restrict__ b_fc,
                          float* __restrict__ logits)
{
  int t = threadIdx.x;
  if (t < 40){
    int b = t/10, k = t - 10*(t/10);
    float a = b_fc[k];
    #pragma unroll 1
    for (int c=0;c<64;++c) a = fmaf(pooled[b*64+c]*(1.f/4096.f), w_fc[k*64+c], a);
    logits[b*10+k] = a;
  }
}

extern "C" void kernel_launch(void* const* d_in, const int* in_sizes, int n_in,
                              void* d_out, int out_size, void* d_ws, size_t ws_size,
                              hipStream_t stream)
{
  const float* x    = (const float*)d_in[0];
  const float* w_p  = (const float*)d_in[1];
  const float* b_p  = (const float*)d_in[2];
  const float* w_m  = (const float*)d_in[3];
  const float* b_m  = (const float*)d_in[4];
  const float* w_dc = (const float*)d_in[5];
  const float* g_d  = (const float*)d_in[6];
  const float* be_d = (const float*)d_in[7];
  const float* w_c1 = (const float*)d_in[8];
  const float* g1   = (const float*)d_in[9];
  const float* be1  = (const float*)d_in[10];
  const float* w_c2 = (const float*)d_in[11];
  const float* g2   = (const float*)d_in[12];
  const float* be2  = (const float*)d_in[13];
  const float* w_fc = (const float*)d_in[14];
  const float* b_fc = (const float*)d_in[15];

  float* out    = (float*)d_out;
  float* logits = out;                 // 40
  float* xxx    = out + 40;            // NV  (stage-2 raw y)
  float* p_out  = out + 40 + NV;       // NV*81

  // workspace layout
  float* ws     = (float*)d_ws;
  float* inp    = ws;                        // NV fp32
  float* stats  = inp + NV;                  // 128
  float* pooled = stats + 128;               // 256
  short* wbf    = (short*)(pooled + 256);    // 27*64*32 bf16
  short* h1bf   = wbf + 27*64*32;            // 4*32*SS bf16
  short* t2bf   = h1bf + (size_t)4*32*SS;    // 4*64*SS bf16
  float* y1     = (float*)t2bf;              // NV fp32, aliases t2bf (dead before conv2)

  const int nblk = (NV + 255)/256;     // 1728

  // conv2 weight repack (independent)
  wconv_kernel<<<(27*64*32+255)/256,256,0,stream>>>(w_c2, wbf);

  // ---- deform stage 1 ----
  deform_kernel<false><<<nblk,256,0,stream>>>(x, w_p,b_p,w_m,b_m,w_dc, y1, nullptr);
  hipMemsetAsync(stats, 0, 2*sizeof(float), stream);
  bn_stats_kernel<<<dim3(64,1),256,0,stream>>>(y1, 1, stats);
  bn_relu_kernel<<<nblk,256,0,stream>>>(y1, inp, stats, g_d, be_d, 1);

  // ---- deform stage 2 (writes xxx and p) ----
  deform_kernel<true><<<nblk,256,0,stream>>>(inp, w_p,b_p,w_m,b_m,w_dc, xxx, p_out);
  hipMemsetAsync(stats, 0, 2*sizeof(float), stream);
  bn_stats_kernel<<<dim3(64,1),256,0,stream>>>(xxx, 1, stats);
  bn_relu_kernel<<<nblk,256,0,stream>>>(xxx, inp, stats, g_d, be_d, 1);

  // ---- conv1 (fp32 in, bf16 out) + BN + relu in place ----
  conv1_kernel<<<nblk,256,0,stream>>>(inp, w_c1, h1bf);
  hipMemsetAsync(stats, 0, 64*sizeof(float), stream);
  bn_stats_bf16<<<dim3(64,32),256,0,stream>>>(h1bf, 32, stats);
  {
    int nb8 = (int)(((size_t)BSZ*32*(SS/8) + 255)/256);
    bn_relu_bf16<<<nb8,256,0,stream>>>(h1bf, stats, g1, be1, 32);
  }

  // ---- conv2 via MFMA (all 64 channels), then BN stats + pool fused ----
  conv2_mfma<<<1728,256,0,stream>>>(h1bf, wbf, t2bf);
  hipMemsetAsync(stats, 0, 128*sizeof(float), stream);
  bn_stats_bf16<<<dim3(64,64),256,0,stream>>>(t2bf, 64, stats);
  hipMemsetAsync(pooled, 0, 256*sizeof(float), stream);
  pool64_kernel<<<dim3(16,64,BSZ),256,0,stream>>>(t2bf, stats, g2, be2, pooled);

  // ---- FC head ----
  fc_kernel<<<1,64,0,stream>>>(pooled, w_fc, b_fc, logits);
}

// Round 3
// 527.837 us; speedup vs baseline: 5.2899x; 1.6456x over previous
//
#include <hip/hip_runtime.h>
#include <math.h>

#define BSZ 4
#define DD 48
#define SS (48*48*48)          // 110592 spatial per (b, channel)
#define NV (BSZ*SS)            // 442368 voxels per channel over batch
#define EPSBN 1e-5f

typedef __attribute__((ext_vector_type(8))) short bf16x8;
typedef __attribute__((ext_vector_type(4))) float f32x4;

__device__ __forceinline__ float sigmoidf_(float x){ return 1.f/(1.f+expf(-x)); }
__device__ __forceinline__ short f2b(float f){           // fp32 -> bf16 bits (RNE)
  unsigned u = __float_as_uint(f);
  u = (u + 0x7FFFu + ((u>>16)&1u)) >> 16;
  return (short)u;
}
__device__ __forceinline__ float b2f(short s){
  return __uint_as_float(((unsigned)(unsigned short)s)<<16);
}

// ---------------- deformable conv stage ----------------
// Weights read straight from global (wave-uniform -> scalar loads).
// WRITE_P: offsets staged in LDS as fp16, p written coalesced in epilogue.
template<bool WRITE_P>
__global__ __launch_bounds__(256) void deform_kernel(
    const float* __restrict__ x,
    const float* __restrict__ w_p, const float* __restrict__ b_p,
    const float* __restrict__ w_m, const float* __restrict__ b_m,
    const float* __restrict__ w_dc,
    float* __restrict__ y, float* __restrict__ p_out)
{
  __shared__ _Float16 hbuf[WRITE_P ? 256*81 : 1];   // 41472 B when WRITE_P

  int tid = threadIdx.x;
  int idx = blockIdx.x*blockDim.x + tid;            // grid covers NV exactly
  int b = idx / SS; int s = idx - b*SS;
  int d = s / (DD*DD); int r2 = s - d*DD*DD; int h = r2/DD; int w = r2 - h*DD;
  const float* xb = x + (size_t)b*SS;

  // 3x3x3 neighborhood (zero-padded) for offset/mask convs
  float nb[27];
  #pragma unroll
  for (int kd=0;kd<3;++kd)
  #pragma unroll
  for (int kh=0;kh<3;++kh)
  #pragma unroll
  for (int kw=0;kw<3;++kw){
    int zz=d+kd-1, yy=h+kh-1, xx=w+kw-1;
    bool ok = ((unsigned)zz<48u)&&((unsigned)yy<48u)&&((unsigned)xx<48u);
    nb[kd*9+kh*3+kw] = ok ? xb[(zz*48+yy)*48+xx] : 0.f;
  }

  float acc = 0.f;
  #pragma unroll 1
  for (int n=0;n<27;++n){
    float od=b_p[n], oh=b_p[27+n], ow=b_p[54+n], mm=b_m[n];
    #pragma unroll
    for (int t=0;t<27;++t){
      float v=nb[t];
      od = fmaf(w_p[ n     *27+t], v, od);
      oh = fmaf(w_p[(27+n)*27+t], v, oh);
      ow = fmaf(w_p[(54+n)*27+t], v, ow);
      mm = fmaf(w_m[ n     *27+t], v, mm);
    }
    mm = sigmoidf_(mm);
    if constexpr (WRITE_P){
      hbuf[tid*81 + n]      = (_Float16)od;
      hbuf[tid*81 + 27 + n] = (_Float16)oh;
      hbuf[tid*81 + 54 + n] = (_Float16)ow;
    }
    int kd=n/9; int kh=(n-kd*9)/3; int kw=n-kd*9-kh*3;
    float pd=(float)(d+kd)+od, ph=(float)(h+kh)+oh, pw=(float)(w+kw)+ow;

    float d0=fminf(fmaxf(floorf(pd),0.f),49.f); float d1=fminf(d0+1.f,49.f);
    float pdc=fminf(fmaxf(pd,0.f),49.f);
    float wd0=1.f+d0-pdc, wd1=1.f-d1+pdc;
    float h0=fminf(fmaxf(floorf(ph),0.f),49.f); float h1v=fminf(h0+1.f,49.f);
    float phc=fminf(fmaxf(ph,0.f),49.f);
    float wh0=1.f+h0-phc, wh1=1.f-h1v+phc;
    float w0=fminf(fmaxf(floorf(pw),0.f),49.f); float w1v=fminf(w0+1.f,49.f);
    float pwc=fminf(fmaxf(pw,0.f),49.f);
    float ww0=1.f+w0-pwc, ww1=1.f-w1v+pwc;

    int id0=(int)d0-1, id1=(int)d1-1;
    int ih0=(int)h0-1, ih1=(int)h1v-1;
    int iw0=(int)w0-1, iw1=(int)w1v-1;

    auto smp=[&](int z,int yy2,int xx2)->float{
      return (((unsigned)z<48u)&&((unsigned)yy2<48u)&&((unsigned)xx2<48u))
               ? xb[(z*48+yy2)*48+xx2] : 0.f;
    };
    float v000=smp(id0,ih0,iw0), v001=smp(id0,ih0,iw1);
    float v010=smp(id0,ih1,iw0), v011=smp(id0,ih1,iw1);
    float v100=smp(id1,ih0,iw0), v101=smp(id1,ih0,iw1);
    float v110=smp(id1,ih1,iw0), v111=smp(id1,ih1,iw1);
    float sv = wd0*(wh0*(ww0*v000+ww1*v001)+wh1*(ww0*v010+ww1*v011))
             + wd1*(wh0*(ww0*v100+ww1*v101)+wh1*(ww0*v110+ww1*v111));
    acc += sv*mm*w_dc[n];
  }
  y[idx]=acc;

  if constexpr (WRITE_P){
    __syncthreads();
    float* pblock = p_out + (size_t)blockIdx.x*(256*81);
    #pragma unroll 1
    for (int j=0;j<81;++j){
      int m = tid + 256*j;
      int t = m/81; int o = m - t*81;
      int comp = o/27; int tap = o - comp*27;
      int vi = blockIdx.x*256 + t;
      int s2 = vi - (vi/SS)*SS;
      int dd2 = s2/(48*48); int rr = s2 - dd2*2304; int hh = rr/48; int ww2 = rr - hh*48;
      int kd = tap/9; int kh2 = (tap - kd*9)/3; int kw2 = tap - kd*9 - kh2*3;
      int base = (comp==0) ? (dd2+kd) : ((comp==1) ? (hh+kh2) : (ww2+kw2));
      float val = (float)base + (float)hbuf[m];
      pblock[m] = fminf(fmaxf(val, 0.f), 49.f);   // coalesced 256B/wave store
    }
  }
}

// ---------------- BN stats fp32 (deform stages, nch=1) ----------------
__global__ __launch_bounds__(256) void bn_stats_kernel(
    const float* __restrict__ x, int nch, float* __restrict__ sums)
{
  int c = blockIdx.y;
  float s1=0.f, s2=0.f;
  for (int i=blockIdx.x*blockDim.x+threadIdx.x; i<NV; i+=gridDim.x*blockDim.x){
    int b=i/SS; int s=i-b*SS;
    float v = x[((size_t)b*nch+c)*SS + s];
    s1+=v; s2+=v*v;
  }
  __shared__ float r1[256], r2[256];
  r1[threadIdx.x]=s1; r2[threadIdx.x]=s2; __syncthreads();
  for (int o=128;o>0;o>>=1){
    if (threadIdx.x<o){ r1[threadIdx.x]+=r1[threadIdx.x+o]; r2[threadIdx.x]+=r2[threadIdx.x+o]; }
    __syncthreads();
  }
  if (threadIdx.x==0){ atomicAdd(&sums[2*c],r1[0]); atomicAdd(&sums[2*c+1],r2[0]); }
}

// ---------------- BN normalize + relu fp32 (deform stages) ----------------
__global__ __launch_bounds__(256) void bn_relu_kernel(
    const float* __restrict__ x, float* __restrict__ out,
    const float* __restrict__ sums, const float* __restrict__ gamma,
    const float* __restrict__ beta, int nch)
{
  size_t idx = (size_t)blockIdx.x*blockDim.x + threadIdx.x;
  size_t total = (size_t)BSZ*nch*SS;
  if (idx>=total) return;
  int c = (int)((idx/SS)%nch);
  float mu  = sums[2*c]  *(1.f/(float)NV);
  float var = sums[2*c+1]*(1.f/(float)NV) - mu*mu;
  float v = (x[idx]-mu)*rsqrtf(var+EPSBN)*gamma[c]+beta[c];
  out[idx] = fmaxf(v,0.f);
}

// ---------------- BN stats over bf16 tensor ----------------
__global__ __launch_bounds__(256) void bn_stats_bf16(
    const short* __restrict__ x, int nch, float* __restrict__ sums)
{
  int c = blockIdx.y;
  const int S8 = SS/8;
  float s1=0.f, s2=0.f;
  for (int i8=blockIdx.x*blockDim.x+threadIdx.x; i8<BSZ*S8; i8+=gridDim.x*blockDim.x){
    int b=i8/S8; int s8=i8-b*S8;
    const bf16x8 v8 = *(const bf16x8*)(x + ((size_t)b*nch+c)*SS + (size_t)s8*8);
    #pragma unroll
    for (int j=0;j<8;++j){ float v=b2f(v8[j]); s1+=v; s2+=v*v; }
  }
  __shared__ float r1[256], r2[256];
  r1[threadIdx.x]=s1; r2[threadIdx.x]=s2; __syncthreads();
  for (int o=128;o>0;o>>=1){
    if (threadIdx.x<o){ r1[threadIdx.x]+=r1[threadIdx.x+o]; r2[threadIdx.x]+=r2[threadIdx.x+o]; }
    __syncthreads();
  }
  if (threadIdx.x==0){ atomicAdd(&sums[2*c],r1[0]); atomicAdd(&sums[2*c+1],r2[0]); }
}

// ---------------- BN + relu in place over bf16 tensor ----------------
__global__ __launch_bounds__(256) void bn_relu_bf16(
    short* __restrict__ x, const float* __restrict__ sums,
    const float* __restrict__ gamma, const float* __restrict__ beta, int nch)
{
  const int S8 = SS/8;
  size_t i8 = (size_t)blockIdx.x*blockDim.x + threadIdx.x;
  size_t total8 = (size_t)BSZ*nch*S8;
  if (i8>=total8) return;
  int c = (int)((i8/S8)%nch);
  float mu  = sums[2*c]  *(1.f/(float)NV);
  float var = sums[2*c+1]*(1.f/(float)NV) - mu*mu;
  float sc = rsqrtf(var+EPSBN)*gamma[c];
  float sh = beta[c] - mu*sc;
  bf16x8 v8 = *(bf16x8*)(x + i8*8);
  #pragma unroll
  for (int j=0;j<8;++j){
    float v = fmaxf(fmaf(b2f(v8[j]),sc,sh),0.f);
    v8[j] = f2b(v);
  }
  *(bf16x8*)(x + i8*8) = v8;
}

// ---------------- conv1: 1 -> 32 channels, fp32 in, bf16 out ----------------
__global__ __launch_bounds__(256) void conv1_kernel(
    const float* __restrict__ x, const float* __restrict__ wt, short* __restrict__ out)
{
  __shared__ float sw[32*27];
  for (int i=threadIdx.x;i<32*27;i+=blockDim.x) sw[i]=wt[i];
  __syncthreads();
  int idx = blockIdx.x*blockDim.x + threadIdx.x;
  if (idx >= NV) return;
  int b = idx / SS; int s = idx - b*SS;
  int d = s / (DD*DD); int r2 = s - d*DD*DD; int h = r2/DD; int w = r2 - h*DD;
  const float* xb = x + (size_t)b*SS;
  float nb[27];
  #pragma unroll
  for (int kd=0;kd<3;++kd)
  #pragma unroll
  for (int kh=0;kh<3;++kh)
  #pragma unroll
  for (int kw=0;kw<3;++kw){
    int zz=d+kd-1, yy=h+kh-1, xx=w+kw-1;
    bool ok = ((unsigned)zz<48u)&&((unsigned)yy<48u)&&((unsigned)xx<48u);
    nb[kd*9+kh*3+kw] = ok ? xb[(zz*48+yy)*48+xx] : 0.f;
  }
  #pragma unroll 1
  for (int c=0;c<32;++c){
    float a=0.f;
    #pragma unroll
    for (int t=0;t<27;++t) a = fmaf(sw[c*27+t], nb[t], a);
    out[((size_t)b*32+c)*SS + s] = f2b(a);
  }
}

// ---------------- conv2 weight repack: (co,ci,tap) fp32 -> (tap,co,ci) bf16 ----
__global__ void wconv_kernel(const float* __restrict__ w, short* __restrict__ wbf)
{
  int o = blockIdx.x*blockDim.x + threadIdx.x;
  if (o >= 27*64*32) return;
  int ci = o & 31; int co = (o>>5) & 63; int tap = o >> 11;
  wbf[o] = f2b(w[(co*32+ci)*27 + tap]);
}

// ---------------- conv2 via MFMA: 32 -> 64 channels, bf16 ----------------
__global__ __launch_bounds__(256) void conv2_mfma(
    const short* __restrict__ h1, const short* __restrict__ wbf,
    short* __restrict__ t2)
{
  __shared__ __align__(16) short slab[6*6*18*32];  // 41472 B
  int bid = blockIdx.x;
  int bw = bid % 3; int bh = (bid/3)%12; int bd = (bid/36)%12; int b = bid/432;
  int d0 = bd*4, h0 = bh*4, w0 = bw*16;
  int tid = threadIdx.x;
  const short* hb = h1 + (size_t)b*32*SS;

  for (int e = tid; e < 648; e += 256){
    int z = e/108; int rem = e - z*108; int y = rem/18; int x = rem - y*18;
    int gd = d0-1+z, gh = h0-1+y, gw = w0-1+x;
    bool ok = ((unsigned)gd<48u)&&((unsigned)gh<48u)&&((unsigned)gw<48u);
    int gbase = ok ? (gd*48+gh)*48+gw : 0;
    int swz = (x&3)<<3;
    int lbase = e*32;
    #pragma unroll
    for (int ci=0; ci<32; ci+=2){
      short v0 = ok ? hb[(size_t)ci*SS + gbase] : (short)0;
      short v1 = ok ? hb[(size_t)(ci+1)*SS + gbase] : (short)0;
      int p0 = ci ^ swz;
      slab[lbase + p0]     = v0;
      slab[lbase + p0 + 1] = v1;
    }
  }
  __syncthreads();

  int lane = tid & 63, wid = tid >> 6;
  int q = lane >> 4, n16 = lane & 15;
  f32x4 zero4 = {0.f,0.f,0.f,0.f};
  f32x4 acc[4][4];
  #pragma unroll
  for (int i=0;i<4;++i)
  #pragma unroll
  for (int j=0;j<4;++j) acc[i][j] = zero4;

  #pragma unroll 1
  for (int tap=0; tap<27; ++tap){
    int kd = tap/9; int kh = (tap/3)%3; int kw = tap%3;
    const short* wp = wbf + (size_t)tap*64*32 + n16*32 + q*8;
    bf16x8 aF[4];
    #pragma unroll
    for (int mb=0; mb<4; ++mb)
      aF[mb] = *(const bf16x8*)(wp + mb*16*32);

    int xx = n16 + kw;
    int cof = (q ^ (xx&3)) << 3;
    int zz = wid + kd;
    bf16x8 bF[4];
    #pragma unroll
    for (int dy=0; dy<4; ++dy){
      int yy = dy + kh;
      bF[dy] = *(const bf16x8*)&slab[ ((zz*6 + yy)*18 + xx)*32 + cof ];
    }
    #pragma unroll
    for (int mb=0; mb<4; ++mb)
      #pragma unroll
      for (int dy=0; dy<4; ++dy)
        acc[mb][dy] = __builtin_amdgcn_mfma_f32_16x16x32_bf16(aF[mb], bF[dy], acc[mb][dy], 0,0,0);
  }

  int d = d0 + wid;
  #pragma unroll
  for (int mb=0; mb<4; ++mb)
  #pragma unroll
  for (int dy=0; dy<4; ++dy){
    int h = h0 + dy, w = w0 + n16;
    #pragma unroll
    for (int r=0; r<4; ++r){
      int c = mb*16 + q*4 + r;
      t2[ (size_t)(b*64+c)*SS + (d*48+h)*48 + w ] = f2b(acc[mb][dy][r]);
    }
  }
}

// ---------------- BN + relu + 3^3/3 maxpool + spatial-sum (bf16 in) ----------
__global__ __launch_bounds__(256) void pool64_kernel(
    const short* __restrict__ t2, const float* __restrict__ sums,
    const float* __restrict__ gamma, const float* __restrict__ beta,
    float* __restrict__ pooled)
{
  int b = blockIdx.z, c = blockIdx.y;
  int cell = blockIdx.x*blockDim.x + threadIdx.x;   // 0..4095
  int pd = cell>>8; int rr = cell&255; int phh = rr>>4; int pww = rr&15;
  float mu  = sums[2*c]  *(1.f/(float)NV);
  float var = sums[2*c+1]*(1.f/(float)NV) - mu*mu;
  float sc  = rsqrtf(var+EPSBN)*gamma[c];
  float sh  = beta[c] - mu*sc;
  const short* base = t2 + ((size_t)b*64+c)*SS;
  float mx = -1e30f;
  #pragma unroll
  for (int kd=0;kd<3;++kd)
  #pragma unroll
  for (int kh=0;kh<3;++kh)
  #pragma unroll
  for (int kw=0;kw<3;++kw){
    float v = b2f(base[((pd*3+kd)*48 + (phh*3+kh))*48 + (pww*3+kw)]);
    v = fmaxf(fmaf(v,sc,sh), 0.f);
    mx = fmaxf(mx, v);
  }
  __shared__ float r[256];
  r[threadIdx.x]=mx; __syncthreads();
  for (int o=128;o>0;o>>=1){
    if (threadIdx.x<o) r[threadIdx.x]+=r[threadIdx.x+o];
    __syncthreads();
  }
  if (threadIdx.x==0) atomicAdd(&pooled[b*64+c], r[0]);
}

// ---------------- FC head ----------------
__global__ void fc_kernel(const float* __restrict__ pooled,
                          const float* __restrict__ w_fc, const float* __restrict__ b_fc,
                          float* __restrict__ logits)
{
  int t = threadIdx.x;
  if (t < 40){
    int b = t/10, k = t - 10*(t/10);
    float a = b_fc[k];
    #pragma unroll 1
    for (int c=0;c<64;++c) a = fmaf(pooled[b*64+c]*(1.f/4096.f), w_fc[k*64+c], a);
    logits[b*10+k] = a;
  }
}

extern "C" void kernel_launch(void* const* d_in, const int* in_sizes, int n_in,
                              void* d_out, int out_size, void* d_ws, size_t ws_size,
                              hipStream_t stream)
{
  const float* x    = (const float*)d_in[0];
  const float* w_p  = (const float*)d_in[1];
  const float* b_p  = (const float*)d_in[2];
  const float* w_m  = (const float*)d_in[3];
  const float* b_m  = (const float*)d_in[4];
  const float* w_dc = (const float*)d_in[5];
  const float* g_d  = (const float*)d_in[6];
  const float* be_d = (const float*)d_in[7];
  const float* w_c1 = (const float*)d_in[8];
  const float* g1   = (const float*)d_in[9];
  const float* be1  = (const float*)d_in[10];
  const float* w_c2 = (const float*)d_in[11];
  const float* g2   = (const float*)d_in[12];
  const float* be2  = (const float*)d_in[13];
  const float* w_fc = (const float*)d_in[14];
  const float* b_fc = (const float*)d_in[15];

  float* out    = (float*)d_out;
  float* logits = out;                 // 40
  float* xxx    = out + 40;            // NV  (stage-2 raw y)
  float* p_out  = out + 40 + NV;       // NV*81

  // workspace layout
  float* ws     = (float*)d_ws;
  float* inp    = ws;                        // NV fp32
  float* stats  = inp + NV;                  // 128
  float* pooled = stats + 128;               // 256
  short* wbf    = (short*)(pooled + 256);    // 27*64*32 bf16
  short* h1bf   = wbf + 27*64*32;            // 4*32*SS bf16
  short* t2bf   = h1bf + (size_t)4*32*SS;    // 4*64*SS bf16
  float* y1     = (float*)t2bf;              // NV fp32, aliases t2bf (dead before conv2)

  const int nblk = (NV + 255)/256;     // 1728

  // conv2 weight repack (independent)
  wconv_kernel<<<(27*64*32+255)/256,256,0,stream>>>(w_c2, wbf);

  // ---- deform stage 1 ----
  deform_kernel<false><<<nblk,256,0,stream>>>(x, w_p,b_p,w_m,b_m,w_dc, y1, nullptr);
  hipMemsetAsync(stats, 0, 2*sizeof(float), stream);
  bn_stats_kernel<<<dim3(64,1),256,0,stream>>>(y1, 1, stats);
  bn_relu_kernel<<<nblk,256,0,stream>>>(y1, inp, stats, g_d, be_d, 1);

  // ---- deform stage 2 (writes xxx and p) ----
  deform_kernel<true><<<nblk,256,0,stream>>>(inp, w_p,b_p,w_m,b_m,w_dc, xxx, p_out);
  hipMemsetAsync(stats, 0, 2*sizeof(float), stream);
  bn_stats_kernel<<<dim3(64,1),256,0,stream>>>(xxx, 1, stats);
  bn_relu_kernel<<<nblk,256,0,stream>>>(xxx, inp, stats, g_d, be_d, 1);

  // ---- conv1 (fp32 in, bf16 out) + BN + relu in place ----
  conv1_kernel<<<nblk,256,0,stream>>>(inp, w_c1, h1bf);
  hipMemsetAsync(stats, 0, 64*sizeof(float), stream);
  bn_stats_bf16<<<dim3(64,32),256,0,stream>>>(h1bf, 32, stats);
  {
    int nb8 = (int)(((size_t)BSZ*32*(SS/8) + 255)/256);
    bn_relu_bf16<<<nb8,256,0,stream>>>(h1bf, stats, g1, be1, 32);
  }

  // ---- conv2 via MFMA (all 64 channels), then BN stats + pool fused ----
  conv2_mfma<<<1728,256,0,stream>>>(h1bf, wbf, t2bf);
  hipMemsetAsync(stats, 0, 128*sizeof(float), stream);
  bn_stats_bf16<<<dim3(64,64),256,0,stream>>>(t2bf, 64, stats);
  hipMemsetAsync(pooled, 0, 256*sizeof(float), stream);
  pool64_kernel<<<dim3(16,64,BSZ),256,0,stream>>>(t2bf, stats, g2, be2, pooled);

  // ---- FC head ----
  fc_kernel<<<1,64,0,stream>>>(pooled, w_fc, b_fc, logits);
}